// Round 2
// baseline (100.412 us; speedup 1.0000x reference)
//
#include <hip/hip_runtime.h>
#include <cstdint>

#define NW 10
#define NOPS 30

// ---------------------------------------------------------------------------
// Constexpr numpy RNG (SeedSequence + PCG64 XSL-RR), canary-certified (R5/R6).
// ---------------------------------------------------------------------------
namespace {

typedef unsigned __int128 u128;

struct CRng { u128 state; u128 inc; bool has32; uint32_t cached; };

constexpr u128 PCG_MUL = (((u128)0x2360ED051FC65DA4ULL) << 64) | (u128)0x4385DF649FCCF645ULL;

constexpr void cr_step(CRng &r) { r.state = r.state * PCG_MUL + r.inc; }

constexpr uint64_t cr_out(u128 st) {
  uint64_t hi = (uint64_t)(st >> 64);
  uint64_t lo = (uint64_t)st;
  unsigned rot = (unsigned)(st >> 122) & 63u;
  uint64_t v = hi ^ lo;
  return (v >> rot) | (v << ((64u - rot) & 63u));
}

constexpr uint64_t cr_next64(CRng &r) { cr_step(r); return cr_out(r.state); }

constexpr uint32_t cr_next32(CRng &r) {
  if (r.has32) { r.has32 = false; return r.cached; }
  uint64_t v = cr_next64(r);
  r.has32 = true; r.cached = (uint32_t)(v >> 32);
  return (uint32_t)v;
}

constexpr CRng cr_seed(uint32_t ent) {
  uint32_t pool[4] = {0u, 0u, 0u, 0u};
  uint32_t hc = 0x43b0d7e5u;              // INIT_A
  for (int i = 0; i < 4; i++) {
    uint32_t v = (i == 0) ? ent : 0u;
    v ^= hc; hc *= 0x931e8875u; v *= hc; v ^= v >> 16;
    pool[i] = v;
  }
  for (int s = 0; s < 4; s++)
    for (int d = 0; d < 4; d++)
      if (s != d) {
        uint32_t v = pool[s];
        v ^= hc; hc *= 0x931e8875u; v *= hc; v ^= v >> 16;        // hashmix
        uint32_t res = 0xca01f9ddu * pool[d] - 0x4973f715u * v;   // mix (SUB)
        res ^= res >> 16;
        pool[d] = res;
      }
  uint32_t hb = 0x8b51f9ddu;              // INIT_B
  uint64_t s64[4] = {0ull, 0ull, 0ull, 0ull};
  for (int i = 0; i < 8; i++) {
    uint32_t d = pool[i & 3];
    d ^= hb; hb *= 0x58f38dedu; d *= hb; d ^= d >> 16;
    if (i & 1) s64[i >> 1] |= ((uint64_t)d << 32); else s64[i >> 1] = (uint64_t)d;
  }
  CRng r{};
  u128 initstate = (((u128)s64[0]) << 64) | (u128)s64[1];
  u128 initseq   = (((u128)s64[2]) << 64) | (u128)s64[3];
  r.state = 0; r.inc = (initseq << 1) | (u128)1;
  cr_step(r);
  r.state += initstate;
  cr_step(r);
  r.has32 = false; r.cached = 0u;
  return r;
}

constexpr uint32_t cr_lemire32(CRng &r, uint32_t rng) {
  uint32_t rng_excl = rng + 1u;
  uint64_t m = (uint64_t)cr_next32(r) * (uint64_t)rng_excl;
  uint32_t leftover = (uint32_t)m;
  if (leftover < rng_excl) {
    uint32_t threshold = (uint32_t)(0xFFFFFFFFu - rng) % rng_excl;
    while (leftover < threshold) {
      m = (uint64_t)cr_next32(r) * (uint64_t)rng_excl;
      leftover = (uint32_t)m;
    }
  }
  return (uint32_t)(m >> 32);
}

constexpr bool canary_pcg42() {
  CRng r = cr_seed(42u);
  double a = (double)(cr_next64(r) >> 11) * (1.0 / 9007199254740992.0);
  double b = (double)(cr_next64(r) >> 11) * (1.0 / 9007199254740992.0);
  double c = (double)(cr_next64(r) >> 11) * (1.0 / 9007199254740992.0);
  bool ok = (a > 0.77395603) && (a < 0.77395607);
  ok = ok && (b > 0.43887842) && (b < 0.43887846);
  ok = ok && (c > 0.85859790) && (c < 0.85859794);
  return ok;
}
static_assert(canary_pcg42(), "CANARY_PCG_SEED42_RANDOM_MISMATCH");

// ---- compile-time circuit (WIRE indices; kind 0 RX,1 RY,2 RZ,3 CNOT) ------
struct COp { int kind; int a; int b; int slot; };
struct Circ { COp op[NOPS]; };

constexpr Circ build_circuit() {
  Circ c{};
  CRng r = cr_seed(42u);
  for (int i = 0; i < NOPS; i++) {
    int k = (int)cr_lemire32(r, 3u);            // integers(0,4)
    if (k == 3) {
      uint32_t v8 = cr_lemire32(r, 8u);         // Floyd j=8
      uint32_t v9 = cr_lemire32(r, 9u);         // Floyd j=9
      uint32_t i0 = v8;
      uint32_t i1 = (v9 == v8) ? 9u : v9;
      uint32_t j = cr_lemire32(r, 1u);          // shuffle swap bit
      if (j == 0u) { uint32_t t = i0; i0 = i1; i1 = t; }
      c.op[i] = COp{3, (int)i0, (int)i1, i};    // a=control, b=target
    } else {
      int w = (int)cr_lemire32(r, 9u);          // integers(0,10)
      c.op[i] = COp{k, w, 0, i};
    }
  }
  return c;
}
constexpr Circ CC = build_circuit();

// ---------------------------------------------------------------------------
// Compile-time Heisenberg propagation of H backward through the 30 ops.
// meta: xm[0:10) | zm[10:20) | sign[20] | w[21:25) | src[25:27)
// upk[u]: five 6-bit fields (pair p at bits 6p) holding 4*code_p where
// code_p = x2 | z2<<2 for wires {2p, 2p+1} -> byte offsets into 16-entry
// per-pair factor LUTs built per element at eval time.
// ---------------------------------------------------------------------------
constexpr int MAXP = 16384;
constexpr int MAXU = 4096;

struct Tables {
  int np, nu, overflow;
  uint32_t pmeta[MAXP]; uint32_t pcm[MAXP]; uint32_t psm[MAXP];
  uint32_t ukey[MAXU];  int ustart[MAXU + 1];
  uint32_t upk[MAXU];
};

constexpr Tables build_tables() {
  Tables T{};
  uint32_t meta[MAXP] = {}; uint32_t cm[MAXP] = {}; uint32_t sm[MAXP] = {};
  int np = 0; int ovf = 0;
  for (int w = 0; w < NW; w++)
    for (int src = 0; src < 3; src++) {         // 0:cZ->Z, 1:cX->X, 2:cY->Y
      uint32_t xm = (src != 0) ? (1u << w) : 0u;
      uint32_t zm = (src != 1) ? (1u << w) : 0u;
      meta[np] = xm | (zm << 10) | ((uint32_t)w << 21) | ((uint32_t)src << 25);
      cm[np] = 0u; sm[np] = 0u; np++;
    }
  for (int k = NOPS - 1; k >= 0 && !ovf; k--) {
    const COp op = CC.op[k];
    if (op.kind == 3) {
      const int c = op.a, t = op.b;
      for (int p = 0; p < np; p++) {
        uint32_t m = meta[p];
        uint32_t xm = m & 1023u, zm = (m >> 10) & 1023u;
        uint32_t xc = (xm >> c) & 1u, zc = (zm >> c) & 1u;
        uint32_t xt = (xm >> t) & 1u, zt = (zm >> t) & 1u;
        uint32_t fl = xc & zt & (1u ^ (xt ^ zc));
        xm ^= xc << t;
        zm ^= zt << c;
        m = (m & ~(1023u | (1023u << 10))) | xm | (zm << 10);
        m ^= fl << 20;
        meta[p] = m;
      }
    } else {
      const int q = op.a, ax = op.kind, bit = op.slot;
      const int n0 = np;
      for (int p = 0; p < n0; p++) {
        uint32_t m = meta[p];
        uint32_t x = (m >> q) & 1u;
        uint32_t z = (m >> (10 + q)) & 1u;
        uint32_t viol = (ax == 0) ? z : (ax == 1) ? (x ^ z) : x;
        if (viol) {
          uint32_t nx = 0, nz = 0, fl = 0;
          if (ax == 0)      { if (x) { nx = 0; nz = 1; fl = 1; } else { nx = 1; nz = 1; fl = 0; } }
          else if (ax == 1) { if (x) { nx = 0; nz = 1; fl = 0; } else { nx = 1; nz = 0; fl = 1; } }
          else              { if (z) { nx = 1; nz = 0; fl = 0; } else { nx = 1; nz = 1; fl = 1; } }
          if (np >= MAXP) { ovf = 1; break; }
          uint32_t m2 = m;
          m2 &= ~((1u << q) | (1u << (10 + q)));
          m2 |= (nx << q) | (nz << (10 + q));
          m2 ^= fl << 20;
          meta[np] = m2; cm[np] = cm[p]; sm[np] = sm[p] | (1u << bit);
          np++;
          cm[p] |= 1u << bit;
        }
      }
    }
  }
  if (ovf) { T.overflow = 1; return T; }
  // Y-kill compact
  int n2 = 0;
  for (int p = 0; p < np; p++) {
    uint32_t m = meta[p];
    if ((m & 1023u) & ((m >> 10) & 1023u)) continue;
    meta[n2] = m; cm[n2] = cm[p]; sm[n2] = sm[p]; n2++;
  }
  np = n2;
  // stable 2-pass radix sort of indices by 20-bit key
  int idx[MAXP] = {}; int tmp[MAXP] = {};
  for (int i = 0; i < np; i++) idx[i] = i;
  int hist[1025] = {};
  for (int i = 0; i < 1025; i++) hist[i] = 0;
  for (int i = 0; i < np; i++) hist[1 + (meta[idx[i]] & 1023u)]++;
  for (int i = 0; i < 1024; i++) hist[i + 1] += hist[i];
  for (int i = 0; i < np; i++) tmp[hist[meta[idx[i]] & 1023u]++] = idx[i];
  for (int i = 0; i < 1025; i++) hist[i] = 0;
  for (int i = 0; i < np; i++) hist[1 + ((meta[tmp[i]] >> 10) & 1023u)]++;
  for (int i = 0; i < 1024; i++) hist[i + 1] += hist[i];
  for (int i = 0; i < np; i++) idx[hist[(meta[tmp[i]] >> 10) & 1023u]++] = tmp[i];
  // group + emit
  int nu = 0; uint32_t prev = 0xFFFFFFFFu;
  for (int i = 0; i < np; i++) {
    int p = idx[i];
    uint32_t key = meta[p] & 0xFFFFFu;
    if (key != prev) {
      if (nu >= MAXU) { T.overflow = 2; return T; }
      T.ukey[nu] = key; T.ustart[nu] = i; prev = key; nu++;
    }
    T.pmeta[i] = meta[p]; T.pcm[i] = cm[p]; T.psm[i] = sm[p];
  }
  T.ustart[nu] = np;
  // pack per-unique-string pair-LUT byte offsets (5 pairs x 6 bits)
  for (int u = 0; u < nu; u++) {
    uint32_t key = T.ukey[u]; uint32_t pk = 0;
    for (int p = 0; p < 5; p++) {
      uint32_t x2 = (key >> (2 * p)) & 3u;
      uint32_t z2 = (key >> (10 + 2 * p)) & 3u;
      pk |= ((x2 | (z2 << 2)) << 2) << (6 * p);   // 4*code at bit 6p
    }
    T.upk[u] = pk;
  }
  T.np = np; T.nu = nu; T.overflow = 0;
  return T;
}

constexpr Tables TT = build_tables();
static_assert(TT.overflow == 0, "PAULI_PATH_OVERFLOW_raise_MAXP_or_pivot_to_runtime_tables");
static_assert(TT.nu >= 1 && TT.nu <= MAXU, "PAULI_UNIQUE_COUNT_OUT_OF_RANGE");
constexpr int NU  = TT.nu;
constexpr int NUP = (NU + 1) & ~1;   // pad to even so eval can do 2 strings/iter

} // namespace

__device__ const Tables dTT = TT;

// ---------------------------------------------------------------------------
// FUSED kernel (R2): one dispatch, 1024-thread blocks, 16 elements per block
// (one per wave).  Each block redundantly computes the tiny prep (trig of 30
// angles, tail-fold Pauli coeffs, per-unique-string C_u, collapsed MLP)
// directly into its own LDS -- total redundant FLOPs across the grid are ~2 us
// of vector-ALU aggregate, which buys: no second dispatch, no ws global
// roundtrip, no dependent-launch gap.  (R1 post-mortem: inner-loop VALU cuts
// were neutral -> the non-fill time is launch/roundtrip structure, not math.)
//
// Phases (syncthreads between):
//  1. trig(30 angles), abr tail-fold, head_w stage, r2 = w3*w2 (disjoint tids)
//  2. C_u for all unique strings (tid-strided) ; r1 = r2*w1 (top 64 tids)
//  3. W_eff + const (tids 0..10) ; per-wave pair-LUT build (all lanes)
//  4. eval: 2 strings/iter from LDS, 5 pair-LUT reads each, butterfly reduce
// ---------------------------------------------------------------------------
#define BLOCK 1024
#define WPB   16    // waves (= elements) per block

__global__ __launch_bounds__(BLOCK) void fused_kernel(
    const float* __restrict__ x,
    const float* __restrict__ rand_params,
    const float* __restrict__ rx_theta, const float* __restrict__ ry_theta,
    const float* __restrict__ head_w, const float* __restrict__ head_b,
    const float* __restrict__ w0, const float* __restrict__ b0,
    const float* __restrict__ w1, const float* __restrict__ b1,
    const float* __restrict__ w2, const float* __restrict__ b2,
    const float* __restrict__ w3, const float* __restrict__ b3,
    float* __restrict__ out, int bsz)
{
  __shared__ __align__(16) float2 CKsh[NUP];
  __shared__ float Tbl[WPB][80];      // per-wave: 5 pairs x 16 entries
  __shared__ float ct[32], st[32], abr[3], hwsh[10];
  __shared__ float r2[32], r1[64];
  __shared__ float MLPsh[NW + 1];

  const int tid  = threadIdx.x;
  const int wave = tid >> 6;
  const int lane = tid & 63;

  // ---- phase 1: angle trig + tail fold + head_w + MLP stage r2 ----
  if (tid < NOPS) {
    float t = rand_params[tid];       // FULL angle for Heisenberg conjugation
    ct[tid] = cosf(t);
    st[tid] = sinf(t);
  } else if (tid == 32) {
    // O = M^dag Z M for M = RY(ty) @ RX(tx), Pauli coefficients.
    float tx = rx_theta[0], ty = ry_theta[0];
    abr[0] = cosf(tx) * cosf(ty);     // cZ
    abr[1] = -sinf(ty);               // cX
    abr[2] = sinf(tx) * cosf(ty);     // cY
  } else if (tid >= 64 && tid < 96) {
    const int j = tid - 64;
    float acc = 0.f;
    for (int k = 0; k < 16; k++) acc += w3[k] * w2[k * 32 + j];
    r2[j] = acc;
  } else if (tid >= 96 && tid < 96 + NW) {
    hwsh[tid - 96] = head_w[tid - 96];
  }
  __syncthreads();

  // ---- phase 2: per-unique-string coefficients C_u ; MLP stage r1 ----
  for (int u = tid; u < NU; u += BLOCK) {
    float acc = 0.f;
    const int i0 = dTT.ustart[u], i1 = dTT.ustart[u + 1];
    for (int i = i0; i < i1; i++) {
      uint32_t m = dTT.pmeta[i];
      float v = hwsh[(m >> 21) & 15u] * abr[(m >> 25) & 3u];
      if (m & (1u << 20)) v = -v;
      uint32_t c = dTT.pcm[i];
      while (c) { int b = __builtin_ctz(c); v *= ct[b]; c &= c - 1u; }
      uint32_t s = dTT.psm[i];
      while (s) { int b = __builtin_ctz(s); v *= st[b]; s &= s - 1u; }
      acc += v;
    }
    CKsh[u] = make_float2(acc, __uint_as_float(dTT.upk[u]));
  }
  if (NU < NUP && tid == 0) CKsh[NU] = make_float2(0.f, __uint_as_float(0u));
  if (tid >= BLOCK - 64) {
    const int j = tid - (BLOCK - 64);
    float acc = 0.f;
    for (int k = 0; k < 32; k++) acc += r2[k] * w1[k * 64 + j];
    r1[j] = acc;
  }
  __syncthreads();

  // ---- phase 3: collapsed-MLP W_eff/const ; per-wave pair-LUT build ----
  if (tid < NW) {
    float acc = 0.f;
    for (int k = 0; k < 64; k++) acc += r1[k] * w0[k * NW + tid];
    MLPsh[tid] = acc;
  } else if (tid == NW) {
    float acc = b3[0] + head_b[0];
    for (int k = 0; k < 16; k++) acc += w3[k] * b2[k];
    for (int k = 0; k < 32; k++) acc += r2[k] * b1[k];
    for (int k = 0; k < 64; k++) acc += r1[k] * b0[k];
    MLPsh[NW] = acc;
  }

  const int wv = blockIdx.x * WPB + wave;
  const bool live = (wv < bsz);
  const float* xe = x + wv * NW;
  float* tbl = Tbl[wave];
  if (live) {
    // pair LUTs: entry e = p*16 + code; code = x2 | z2<<2
    {
      const int e = lane;
      const int p = e >> 4, code = e & 15;
      float2 xv = *(const float2*)(xe + 2 * p);           // 8B-aligned (40B rows)
      float c0 = __cosf(xv.x), s0 = __sinf(xv.x);
      float c1 = __cosf(xv.y), s1 = __sinf(xv.y);
      float f0 = (code & 1) ? s0 : ((code & 4) ? c0 : 1.0f);
      float f1 = (code & 2) ? s1 : ((code & 8) ? c1 : 1.0f);
      tbl[e] = f0 * f1;
    }
    if (lane < 16) {
      const int e = lane + 64;
      const int p = e >> 4, code = e & 15;
      float2 xv = *(const float2*)(xe + 2 * p);
      float c0 = __cosf(xv.x), s0 = __sinf(xv.x);
      float c1 = __cosf(xv.y), s1 = __sinf(xv.y);
      float f0 = (code & 1) ? s0 : ((code & 4) ? c0 : 1.0f);
      float f1 = (code & 2) ? s1 : ((code & 8) ? c1 : 1.0f);
      tbl[e] = f0 * f1;
    }
  }
  __syncthreads();
  if (!live) return;

  // ---- phase 4: eval ----
  const char* tb = (const char*)tbl;
  float acc0 = 0.f, acc1 = 0.f;
#pragma unroll 4
  for (int s = 2 * lane; s < NUP; s += 128) {
    float4 q = *(const float4*)&CKsh[s];          // strings s, s+1
    uint32_t ka = __float_as_uint(q.y);
    uint32_t kb = __float_as_uint(q.w);
    float a0 = *(const float*)(tb +       ( ka        & 63u));
    float a1 = *(const float*)(tb +  64 + ((ka >>  6) & 63u));
    float a2 = *(const float*)(tb + 128 + ((ka >> 12) & 63u));
    float a3 = *(const float*)(tb + 192 + ((ka >> 18) & 63u));
    float a4 = *(const float*)(tb + 256 + ((ka >> 24) & 63u));
    float b0v = *(const float*)(tb +       ( kb        & 63u));
    float b1v = *(const float*)(tb +  64 + ((kb >>  6) & 63u));
    float b2v = *(const float*)(tb + 128 + ((kb >> 12) & 63u));
    float b3v = *(const float*)(tb + 192 + ((kb >> 18) & 63u));
    float b4v = *(const float*)(tb + 256 + ((kb >> 24) & 63u));
    acc0 = fmaf(q.x, ((a0 * a1) * (a2 * a3)) * a4, acc0);
    acc1 = fmaf(q.z, ((b0v * b1v) * (b2v * b3v)) * b4v, acc1);
  }
  float acc = acc0 + acc1;

#pragma unroll
  for (int m = 1; m < 64; m <<= 1) acc += __shfl_xor(acc, m);

  if (lane == 0) {
    float cc = MLPsh[NW];
#pragma unroll
    for (int w = 0; w < NW; w++) cc += xe[w] * MLPsh[w];
    out[wv] = acc + cc;
  }
}

extern "C" void kernel_launch(void* const* d_in, const int* in_sizes, int n_in,
                              void* d_out, int out_size, void* d_ws, size_t ws_size,
                              hipStream_t stream) {
  const float* x   = (const float*)d_in[0];
  const float* rp  = (const float*)d_in[1];
  const float* rxT = (const float*)d_in[2];
  const float* ryT = (const float*)d_in[3];
  const float* hw  = (const float*)d_in[4];
  const float* hb  = (const float*)d_in[5];
  const float* w0  = (const float*)d_in[6];
  const float* b0  = (const float*)d_in[7];
  const float* w1  = (const float*)d_in[8];
  const float* b1  = (const float*)d_in[9];
  const float* w2  = (const float*)d_in[10];
  const float* b2  = (const float*)d_in[11];
  const float* w3  = (const float*)d_in[12];
  const float* b3  = (const float*)d_in[13];
  const int bsz = in_sizes[0] / NW;

  const int blocks = (bsz + WPB - 1) / WPB;   // 512 blocks @ bsz=8192 -> 2/CU
  hipLaunchKernelGGL(fused_kernel, dim3(blocks), dim3(BLOCK), 0, stream,
                     x, rp, rxT, ryT, hw, hb, w0, b0, w1, b1, w2, b2, w3, b3,
                     (float*)d_out, bsz);
}

// Round 3
// 91.506 us; speedup vs baseline: 1.0973x; 1.0973x over previous
//
#include <hip/hip_runtime.h>
#include <cstdint>

#define NW 10
#define NOPS 30

// ---------------------------------------------------------------------------
// Constexpr numpy RNG (SeedSequence + PCG64 XSL-RR), canary-certified (R5/R6).
// ---------------------------------------------------------------------------
namespace {

typedef unsigned __int128 u128;

struct CRng { u128 state; u128 inc; bool has32; uint32_t cached; };

constexpr u128 PCG_MUL = (((u128)0x2360ED051FC65DA4ULL) << 64) | (u128)0x4385DF649FCCF645ULL;

constexpr void cr_step(CRng &r) { r.state = r.state * PCG_MUL + r.inc; }

constexpr uint64_t cr_out(u128 st) {
  uint64_t hi = (uint64_t)(st >> 64);
  uint64_t lo = (uint64_t)st;
  unsigned rot = (unsigned)(st >> 122) & 63u;
  uint64_t v = hi ^ lo;
  return (v >> rot) | (v << ((64u - rot) & 63u));
}

constexpr uint64_t cr_next64(CRng &r) { cr_step(r); return cr_out(r.state); }

constexpr uint32_t cr_next32(CRng &r) {
  if (r.has32) { r.has32 = false; return r.cached; }
  uint64_t v = cr_next64(r);
  r.has32 = true; r.cached = (uint32_t)(v >> 32);
  return (uint32_t)v;
}

constexpr CRng cr_seed(uint32_t ent) {
  uint32_t pool[4] = {0u, 0u, 0u, 0u};
  uint32_t hc = 0x43b0d7e5u;              // INIT_A
  for (int i = 0; i < 4; i++) {
    uint32_t v = (i == 0) ? ent : 0u;
    v ^= hc; hc *= 0x931e8875u; v *= hc; v ^= v >> 16;
    pool[i] = v;
  }
  for (int s = 0; s < 4; s++)
    for (int d = 0; d < 4; d++)
      if (s != d) {
        uint32_t v = pool[s];
        v ^= hc; hc *= 0x931e8875u; v *= hc; v ^= v >> 16;        // hashmix
        uint32_t res = 0xca01f9ddu * pool[d] - 0x4973f715u * v;   // mix (SUB)
        res ^= res >> 16;
        pool[d] = res;
      }
  uint32_t hb = 0x8b51f9ddu;              // INIT_B
  uint64_t s64[4] = {0ull, 0ull, 0ull, 0ull};
  for (int i = 0; i < 8; i++) {
    uint32_t d = pool[i & 3];
    d ^= hb; hb *= 0x58f38dedu; d *= hb; d ^= d >> 16;
    if (i & 1) s64[i >> 1] |= ((uint64_t)d << 32); else s64[i >> 1] = (uint64_t)d;
  }
  CRng r{};
  u128 initstate = (((u128)s64[0]) << 64) | (u128)s64[1];
  u128 initseq   = (((u128)s64[2]) << 64) | (u128)s64[3];
  r.state = 0; r.inc = (initseq << 1) | (u128)1;
  cr_step(r);
  r.state += initstate;
  cr_step(r);
  r.has32 = false; r.cached = 0u;
  return r;
}

constexpr uint32_t cr_lemire32(CRng &r, uint32_t rng) {
  uint32_t rng_excl = rng + 1u;
  uint64_t m = (uint64_t)cr_next32(r) * (uint64_t)rng_excl;
  uint32_t leftover = (uint32_t)m;
  if (leftover < rng_excl) {
    uint32_t threshold = (uint32_t)(0xFFFFFFFFu - rng) % rng_excl;
    while (leftover < threshold) {
      m = (uint64_t)cr_next32(r) * (uint64_t)rng_excl;
      leftover = (uint32_t)m;
    }
  }
  return (uint32_t)(m >> 32);
}

constexpr bool canary_pcg42() {
  CRng r = cr_seed(42u);
  double a = (double)(cr_next64(r) >> 11) * (1.0 / 9007199254740992.0);
  double b = (double)(cr_next64(r) >> 11) * (1.0 / 9007199254740992.0);
  double c = (double)(cr_next64(r) >> 11) * (1.0 / 9007199254740992.0);
  bool ok = (a > 0.77395603) && (a < 0.77395607);
  ok = ok && (b > 0.43887842) && (b < 0.43887846);
  ok = ok && (c > 0.85859790) && (c < 0.85859794);
  return ok;
}
static_assert(canary_pcg42(), "CANARY_PCG_SEED42_RANDOM_MISMATCH");

// ---- compile-time circuit (WIRE indices; kind 0 RX,1 RY,2 RZ,3 CNOT) ------
struct COp { int kind; int a; int b; int slot; };
struct Circ { COp op[NOPS]; };

constexpr Circ build_circuit() {
  Circ c{};
  CRng r = cr_seed(42u);
  for (int i = 0; i < NOPS; i++) {
    int k = (int)cr_lemire32(r, 3u);            // integers(0,4)
    if (k == 3) {
      uint32_t v8 = cr_lemire32(r, 8u);         // Floyd j=8
      uint32_t v9 = cr_lemire32(r, 9u);         // Floyd j=9
      uint32_t i0 = v8;
      uint32_t i1 = (v9 == v8) ? 9u : v9;
      uint32_t j = cr_lemire32(r, 1u);          // shuffle swap bit
      if (j == 0u) { uint32_t t = i0; i0 = i1; i1 = t; }
      c.op[i] = COp{3, (int)i0, (int)i1, i};    // a=control, b=target
    } else {
      int w = (int)cr_lemire32(r, 9u);          // integers(0,10)
      c.op[i] = COp{k, w, 0, i};
    }
  }
  return c;
}
constexpr Circ CC = build_circuit();

// ---------------------------------------------------------------------------
// Compile-time Heisenberg propagation of H backward through the 30 ops.
// meta: xm[0:10) | zm[10:20) | sign[20] | w[21:25) | src[25:27)
// upk[u]: five 6-bit fields = byte offsets into runtime 16-entry per-wire-pair
// factor LUTs (eval).  pa/pb/pu[j]: per-PATH packed data in a compile-time
// stride-P permuted order (coalesced reads + scattered u for LDS atomics):
//   pa = g0|g1<<8|g2<<16|g3<<24  (6 groups of 5 op-slots, base-3 codes <243)
//   pb = g4|g5<<8 | w<<16 | src<<20 | sign<<22
//   pu = unique-string index for the atomicAdd target
// ---------------------------------------------------------------------------
constexpr int MAXP = 16384;
constexpr int MAXU = 4096;

struct Tables {
  int np, nu, overflow;
  uint32_t pmeta[MAXP]; uint32_t pcm[MAXP]; uint32_t psm[MAXP];
  uint32_t ukey[MAXU];  int ustart[MAXU + 1];
  uint32_t upk[MAXU];
  uint32_t pa[MAXP]; uint32_t pb[MAXP]; uint16_t pu[MAXP];
};

constexpr Tables build_tables() {
  Tables T{};
  uint32_t meta[MAXP] = {}; uint32_t cm[MAXP] = {}; uint32_t sm[MAXP] = {};
  int np = 0; int ovf = 0;
  for (int w = 0; w < NW; w++)
    for (int src = 0; src < 3; src++) {         // 0:cZ->Z, 1:cX->X, 2:cY->Y
      uint32_t xm = (src != 0) ? (1u << w) : 0u;
      uint32_t zm = (src != 1) ? (1u << w) : 0u;
      meta[np] = xm | (zm << 10) | ((uint32_t)w << 21) | ((uint32_t)src << 25);
      cm[np] = 0u; sm[np] = 0u; np++;
    }
  for (int k = NOPS - 1; k >= 0 && !ovf; k--) {
    const COp op = CC.op[k];
    if (op.kind == 3) {
      const int c = op.a, t = op.b;
      for (int p = 0; p < np; p++) {
        uint32_t m = meta[p];
        uint32_t xm = m & 1023u, zm = (m >> 10) & 1023u;
        uint32_t xc = (xm >> c) & 1u, zc = (zm >> c) & 1u;
        uint32_t xt = (xm >> t) & 1u, zt = (zm >> t) & 1u;
        uint32_t fl = xc & zt & (1u ^ (xt ^ zc));
        xm ^= xc << t;
        zm ^= zt << c;
        m = (m & ~(1023u | (1023u << 10))) | xm | (zm << 10);
        m ^= fl << 20;
        meta[p] = m;
      }
    } else {
      const int q = op.a, ax = op.kind, bit = op.slot;
      const int n0 = np;
      for (int p = 0; p < n0; p++) {
        uint32_t m = meta[p];
        uint32_t x = (m >> q) & 1u;
        uint32_t z = (m >> (10 + q)) & 1u;
        uint32_t viol = (ax == 0) ? z : (ax == 1) ? (x ^ z) : x;
        if (viol) {
          uint32_t nx = 0, nz = 0, fl = 0;
          if (ax == 0)      { if (x) { nx = 0; nz = 1; fl = 1; } else { nx = 1; nz = 1; fl = 0; } }
          else if (ax == 1) { if (x) { nx = 0; nz = 1; fl = 0; } else { nx = 1; nz = 0; fl = 1; } }
          else              { if (z) { nx = 1; nz = 0; fl = 0; } else { nx = 1; nz = 1; fl = 1; } }
          if (np >= MAXP) { ovf = 1; break; }
          uint32_t m2 = m;
          m2 &= ~((1u << q) | (1u << (10 + q)));
          m2 |= (nx << q) | (nz << (10 + q));
          m2 ^= fl << 20;
          meta[np] = m2; cm[np] = cm[p]; sm[np] = sm[p] | (1u << bit);
          np++;
          cm[p] |= 1u << bit;
        }
      }
    }
  }
  if (ovf) { T.overflow = 1; return T; }
  // Y-kill compact
  int n2 = 0;
  for (int p = 0; p < np; p++) {
    uint32_t m = meta[p];
    if ((m & 1023u) & ((m >> 10) & 1023u)) continue;
    meta[n2] = m; cm[n2] = cm[p]; sm[n2] = sm[p]; n2++;
  }
  np = n2;
  // stable 2-pass radix sort of indices by 20-bit key
  int idx[MAXP] = {}; int tmp[MAXP] = {};
  for (int i = 0; i < np; i++) idx[i] = i;
  int hist[1025] = {};
  for (int i = 0; i < 1025; i++) hist[i] = 0;
  for (int i = 0; i < np; i++) hist[1 + (meta[idx[i]] & 1023u)]++;
  for (int i = 0; i < 1024; i++) hist[i + 1] += hist[i];
  for (int i = 0; i < np; i++) tmp[hist[meta[idx[i]] & 1023u]++] = idx[i];
  for (int i = 0; i < 1025; i++) hist[i] = 0;
  for (int i = 0; i < np; i++) hist[1 + ((meta[tmp[i]] >> 10) & 1023u)]++;
  for (int i = 0; i < 1024; i++) hist[i + 1] += hist[i];
  for (int i = 0; i < np; i++) idx[hist[(meta[tmp[i]] >> 10) & 1023u]++] = tmp[i];
  // group + emit (also records per-path unique index)
  uint16_t puTmp[MAXP] = {};
  int nu = 0; uint32_t prev = 0xFFFFFFFFu;
  for (int i = 0; i < np; i++) {
    int p = idx[i];
    uint32_t key = meta[p] & 0xFFFFFu;
    if (key != prev) {
      if (nu >= MAXU) { T.overflow = 2; return T; }
      T.ukey[nu] = key; T.ustart[nu] = i; prev = key; nu++;
    }
    T.pmeta[i] = meta[p]; T.pcm[i] = cm[p]; T.psm[i] = sm[p];
    puTmp[i] = (uint16_t)(nu - 1);
  }
  T.ustart[nu] = np;
  // pack per-unique-string pair-LUT byte offsets (5 pairs x 6 bits)
  for (int u = 0; u < nu; u++) {
    uint32_t key = T.ukey[u]; uint32_t pk = 0;
    for (int p = 0; p < 5; p++) {
      uint32_t x2 = (key >> (2 * p)) & 3u;
      uint32_t z2 = (key >> (10 + 2 * p)) & 3u;
      pk |= ((x2 | (z2 << 2)) << 2) << (6 * p);   // 4*code at bit 6p
    }
    T.upk[u] = pk;
  }
  // per-path packed group codes, stored stride-P permuted (coalesced reads,
  // scattered u -> collision-light LDS atomics).  P coprime with np.
  int P = 997;
  {
    bool ok = false;
    while (!ok) {
      int a = P, b = np;
      while (b) { int t2 = a % b; a = b; b = t2; }
      if (a == 1) ok = true; else P++;
    }
  }
  constexpr int POW3[5] = {1, 3, 9, 27, 81};
  for (int j = 0; j < np; j++) {
    int i = (int)(((long long)j * P) % np);      // source (sorted) index
    uint32_t cmv = T.pcm[i], smv = T.psm[i], m = T.pmeta[i];
    uint32_t g[6] = {0, 0, 0, 0, 0, 0};
    uint32_t mm = cmv;
    while (mm) { int b = __builtin_ctz(mm); mm &= mm - 1u; g[b / 5] += (uint32_t)POW3[b % 5]; }
    mm = smv;
    while (mm) { int b = __builtin_ctz(mm); mm &= mm - 1u; g[b / 5] += 2u * (uint32_t)POW3[b % 5]; }
    T.pa[j] = g[0] | (g[1] << 8) | (g[2] << 16) | (g[3] << 24);
    T.pb[j] = g[4] | (g[5] << 8) | (((m >> 21) & 15u) << 16)
            | (((m >> 25) & 3u) << 20) | (((m >> 20) & 1u) << 22);
    T.pu[j] = puTmp[i];
  }
  T.np = np; T.nu = nu; T.overflow = 0;
  return T;
}

constexpr Tables TT = build_tables();
static_assert(TT.overflow == 0, "PAULI_PATH_OVERFLOW_raise_MAXP_or_pivot_to_runtime_tables");
static_assert(TT.nu >= 1 && TT.nu <= MAXU, "PAULI_UNIQUE_COUNT_OUT_OF_RANGE");
constexpr int NU  = TT.nu;
constexpr int NUP = (NU + 1) & ~1;   // pad to even so eval can do 2 strings/iter
constexpr int NP  = TT.np;

} // namespace

__device__ const Tables dTT = TT;

// ---------------------------------------------------------------------------
// FUSED kernel v2 (R3): one dispatch, 1024-thread blocks, 16 elements/block.
// R2 post-mortem: per-u prep redundancy (skewed path counts -> serial tail at
// every block's barrier) cost +6 us.  v2 prep is PATH-parallel and balanced:
//  - runtime 6x243 product-LUT over 5-op-slot groups (built once per block)
//  - per path: 3 coalesced L2 loads + 6 LDS reads + ~10 VALU + 1 ds_add_f32
//  - compile-time stride-P permutation => coalesced + collision-light atomics
// Phases: A trig/zero/keys/Tbl/r2 | B G-LUT/r1 | C paths+MLP-final | D eval
// ---------------------------------------------------------------------------
#define BLOCK 1024
#define WPB   16    // waves (= elements) per block
#define PWRK  (BLOCK - 16)

__global__ __launch_bounds__(BLOCK) void fused_kernel(
    const float* __restrict__ x,
    const float* __restrict__ rand_params,
    const float* __restrict__ rx_theta, const float* __restrict__ ry_theta,
    const float* __restrict__ head_w, const float* __restrict__ head_b,
    const float* __restrict__ w0, const float* __restrict__ b0,
    const float* __restrict__ w1, const float* __restrict__ b1,
    const float* __restrict__ w2, const float* __restrict__ b2,
    const float* __restrict__ w3, const float* __restrict__ b3,
    float* __restrict__ out, int bsz)
{
  __shared__ __align__(16) float2 CKsh[NUP];
  __shared__ float Gt[6 * 243];       // slot-group product LUT
  __shared__ float Tbl[WPB][80];      // per-wave: 5 wire-pairs x 16 entries
  __shared__ float ct[32], st[32], abr[3], hwsh[10];
  __shared__ float r2[32], r1[64];
  __shared__ float MLPsh[NW + 1];

  const int tid  = threadIdx.x;
  const int wave = tid >> 6;
  const int lane = tid & 63;

  const int wv = blockIdx.x * WPB + wave;
  const bool live = (wv < bsz);
  const float* xe = x + wv * NW;
  float* tbl = Tbl[wave];

  // ---- phase A: angle trig, tail fold, head_w, CK zero+keys, r2, Tbl ----
  if (tid < NOPS) {
    float t = rand_params[tid];       // FULL angle for Heisenberg conjugation
    ct[tid] = cosf(t);
    st[tid] = sinf(t);
  } else if (tid == 32) {
    // O = M^dag Z M for M = RY(ty) @ RX(tx), Pauli coefficients.
    float tx = rx_theta[0], ty = ry_theta[0];
    abr[0] = cosf(tx) * cosf(ty);     // cZ
    abr[1] = -sinf(ty);               // cX
    abr[2] = sinf(tx) * cosf(ty);     // cY
  } else if (tid >= 40 && tid < 40 + NW) {
    hwsh[tid - 40] = head_w[tid - 40];
  } else if (tid >= 64 && tid < 96) {
    const int j = tid - 64;
    float acc = 0.f;
    for (int k = 0; k < 16; k++) acc += w3[k] * w2[k * 32 + j];
    r2[j] = acc;
  }
  for (int i = tid; i < NUP; i += BLOCK)
    CKsh[i] = make_float2(0.f, __uint_as_float(i < NU ? dTT.upk[i] : 0u));
  if (live) {
    // per-wave wire-pair LUTs: entry e = p*16 + code; code = x2 | z2<<2
    {
      const int e = lane;
      const int p = e >> 4, code = e & 15;
      float2 xv = *(const float2*)(xe + 2 * p);           // 8B-aligned (40B rows)
      float c0 = __cosf(xv.x), s0 = __sinf(xv.x);
      float c1 = __cosf(xv.y), s1 = __sinf(xv.y);
      float f0 = (code & 1) ? s0 : ((code & 4) ? c0 : 1.0f);
      float f1 = (code & 2) ? s1 : ((code & 8) ? c1 : 1.0f);
      tbl[e] = f0 * f1;
    }
    if (lane < 16) {
      const int e = lane + 64;
      const int p = e >> 4, code = e & 15;
      float2 xv = *(const float2*)(xe + 2 * p);
      float c0 = __cosf(xv.x), s0 = __sinf(xv.x);
      float c1 = __cosf(xv.y), s1 = __sinf(xv.y);
      float f0 = (code & 1) ? s0 : ((code & 4) ? c0 : 1.0f);
      float f1 = (code & 2) ? s1 : ((code & 8) ? c1 : 1.0f);
      tbl[e] = f0 * f1;
    }
  }
  __syncthreads();

  // ---- phase B: slot-group product LUT; r1 ----
  for (int e = tid; e < 6 * 243; e += BLOCK) {
    const int g = e / 243;
    int c = e - g * 243;
    float v = 1.f;
#pragma unroll
    for (int j = 0; j < 5; j++) {
      int tr = c % 3; c /= 3;
      if (tr == 1) v *= ct[5 * g + j];
      else if (tr == 2) v *= st[5 * g + j];
    }
    Gt[e] = v;
  }
  if (tid >= BLOCK - 64) {
    const int j = tid - (BLOCK - 64);
    float acc = 0.f;
    for (int k = 0; k < 32; k++) acc += r2[k] * w1[k * 64 + j];
    r1[j] = acc;
  }
  __syncthreads();

  // ---- phase C: balanced path scatter (atomic) ; MLP finals ----
  if (tid < NW) {
    float acc = 0.f;
    for (int k = 0; k < 64; k++) acc += r1[k] * w0[k * NW + tid];
    MLPsh[tid] = acc;
  } else if (tid == NW) {
    float acc = b3[0] + head_b[0];
    for (int k = 0; k < 16; k++) acc += w3[k] * b2[k];
    for (int k = 0; k < 32; k++) acc += r2[k] * b1[k];
    for (int k = 0; k < 64; k++) acc += r1[k] * b0[k];
    MLPsh[NW] = acc;
  } else if (tid >= 16) {
    for (int i = tid - 16; i < NP; i += PWRK) {
      uint32_t pa = dTT.pa[i];
      uint32_t pb = dTT.pb[i];
      int      u  = (int)dTT.pu[i];
      float v = hwsh[(pb >> 16) & 15u] * abr[(pb >> 20) & 3u];
      if (pb & (1u << 22)) v = -v;
      v *= Gt[         (pa       ) & 255u] * Gt[1 * 243 + ((pa >>  8) & 255u)];
      v *= Gt[2 * 243 + ((pa >> 16) & 255u)] * Gt[3 * 243 + ( pa >> 24        )];
      v *= Gt[4 * 243 + ( pb        & 255u)] * Gt[5 * 243 + ((pb >>  8) & 255u)];
      atomicAdd(&CKsh[u].x, v);
    }
  }
  __syncthreads();
  if (!live) return;

  // ---- phase D: eval (2 strings/iter; 5 pair-LUT reads per string) ----
  const char* tb = (const char*)tbl;
  float acc0 = 0.f, acc1 = 0.f;
#pragma unroll 4
  for (int s = 2 * lane; s < NUP; s += 128) {
    float4 q = *(const float4*)&CKsh[s];          // strings s, s+1
    uint32_t ka = __float_as_uint(q.y);
    uint32_t kb = __float_as_uint(q.w);
    float a0 = *(const float*)(tb +       ( ka        & 63u));
    float a1 = *(const float*)(tb +  64 + ((ka >>  6) & 63u));
    float a2 = *(const float*)(tb + 128 + ((ka >> 12) & 63u));
    float a3 = *(const float*)(tb + 192 + ((ka >> 18) & 63u));
    float a4 = *(const float*)(tb + 256 + ((ka >> 24) & 63u));
    float b0v = *(const float*)(tb +       ( kb        & 63u));
    float b1v = *(const float*)(tb +  64 + ((kb >>  6) & 63u));
    float b2v = *(const float*)(tb + 128 + ((kb >> 12) & 63u));
    float b3v = *(const float*)(tb + 192 + ((kb >> 18) & 63u));
    float b4v = *(const float*)(tb + 256 + ((kb >> 24) & 63u));
    acc0 = fmaf(q.x, ((a0 * a1) * (a2 * a3)) * a4, acc0);
    acc1 = fmaf(q.z, ((b0v * b1v) * (b2v * b3v)) * b4v, acc1);
  }
  float acc = acc0 + acc1;

#pragma unroll
  for (int m = 1; m < 64; m <<= 1) acc += __shfl_xor(acc, m);

  if (lane == 0) {
    float cc = MLPsh[NW];
#pragma unroll
    for (int w = 0; w < NW; w++) cc += xe[w] * MLPsh[w];
    out[wv] = acc + cc;
  }
}

extern "C" void kernel_launch(void* const* d_in, const int* in_sizes, int n_in,
                              void* d_out, int out_size, void* d_ws, size_t ws_size,
                              hipStream_t stream) {
  const float* x   = (const float*)d_in[0];
  const float* rp  = (const float*)d_in[1];
  const float* rxT = (const float*)d_in[2];
  const float* ryT = (const float*)d_in[3];
  const float* hw  = (const float*)d_in[4];
  const float* hb  = (const float*)d_in[5];
  const float* w0  = (const float*)d_in[6];
  const float* b0  = (const float*)d_in[7];
  const float* w1  = (const float*)d_in[8];
  const float* b1  = (const float*)d_in[9];
  const float* w2  = (const float*)d_in[10];
  const float* b2  = (const float*)d_in[11];
  const float* w3  = (const float*)d_in[12];
  const float* b3  = (const float*)d_in[13];
  const int bsz = in_sizes[0] / NW;

  const int blocks = (bsz + WPB - 1) / WPB;   // 512 blocks @ bsz=8192 -> 2/CU
  hipLaunchKernelGGL(fused_kernel, dim3(blocks), dim3(BLOCK), 0, stream,
                     x, rp, rxT, ryT, hw, hb, w0, b0, w1, b1, w2, b2, w3, b3,
                     (float*)d_out, bsz);
}

// Round 4
// 86.243 us; speedup vs baseline: 1.1643x; 1.0610x over previous
//
#include <hip/hip_runtime.h>
#include <cstdint>

#define NW 10
#define NOPS 30

// ---------------------------------------------------------------------------
// Constexpr numpy RNG (SeedSequence + PCG64 XSL-RR), canary-certified (R5/R6).
// ---------------------------------------------------------------------------
namespace {

typedef unsigned __int128 u128;

struct CRng { u128 state; u128 inc; bool has32; uint32_t cached; };

constexpr u128 PCG_MUL = (((u128)0x2360ED051FC65DA4ULL) << 64) | (u128)0x4385DF649FCCF645ULL;

constexpr void cr_step(CRng &r) { r.state = r.state * PCG_MUL + r.inc; }

constexpr uint64_t cr_out(u128 st) {
  uint64_t hi = (uint64_t)(st >> 64);
  uint64_t lo = (uint64_t)st;
  unsigned rot = (unsigned)(st >> 122) & 63u;
  uint64_t v = hi ^ lo;
  return (v >> rot) | (v << ((64u - rot) & 63u));
}

constexpr uint64_t cr_next64(CRng &r) { cr_step(r); return cr_out(r.state); }

constexpr uint32_t cr_next32(CRng &r) {
  if (r.has32) { r.has32 = false; return r.cached; }
  uint64_t v = cr_next64(r);
  r.has32 = true; r.cached = (uint32_t)(v >> 32);
  return (uint32_t)v;
}

constexpr CRng cr_seed(uint32_t ent) {
  uint32_t pool[4] = {0u, 0u, 0u, 0u};
  uint32_t hc = 0x43b0d7e5u;              // INIT_A
  for (int i = 0; i < 4; i++) {
    uint32_t v = (i == 0) ? ent : 0u;
    v ^= hc; hc *= 0x931e8875u; v *= hc; v ^= v >> 16;
    pool[i] = v;
  }
  for (int s = 0; s < 4; s++)
    for (int d = 0; d < 4; d++)
      if (s != d) {
        uint32_t v = pool[s];
        v ^= hc; hc *= 0x931e8875u; v *= hc; v ^= v >> 16;        // hashmix
        uint32_t res = 0xca01f9ddu * pool[d] - 0x4973f715u * v;   // mix (SUB)
        res ^= res >> 16;
        pool[d] = res;
      }
  uint32_t hb = 0x8b51f9ddu;              // INIT_B
  uint64_t s64[4] = {0ull, 0ull, 0ull, 0ull};
  for (int i = 0; i < 8; i++) {
    uint32_t d = pool[i & 3];
    d ^= hb; hb *= 0x58f38dedu; d *= hb; d ^= d >> 16;
    if (i & 1) s64[i >> 1] |= ((uint64_t)d << 32); else s64[i >> 1] = (uint64_t)d;
  }
  CRng r{};
  u128 initstate = (((u128)s64[0]) << 64) | (u128)s64[1];
  u128 initseq   = (((u128)s64[2]) << 64) | (u128)s64[3];
  r.state = 0; r.inc = (initseq << 1) | (u128)1;
  cr_step(r);
  r.state += initstate;
  cr_step(r);
  r.has32 = false; r.cached = 0u;
  return r;
}

constexpr uint32_t cr_lemire32(CRng &r, uint32_t rng) {
  uint32_t rng_excl = rng + 1u;
  uint64_t m = (uint64_t)cr_next32(r) * (uint64_t)rng_excl;
  uint32_t leftover = (uint32_t)m;
  if (leftover < rng_excl) {
    uint32_t threshold = (uint32_t)(0xFFFFFFFFu - rng) % rng_excl;
    while (leftover < threshold) {
      m = (uint64_t)cr_next32(r) * (uint64_t)rng_excl;
      leftover = (uint32_t)m;
    }
  }
  return (uint32_t)(m >> 32);
}

constexpr bool canary_pcg42() {
  CRng r = cr_seed(42u);
  double a = (double)(cr_next64(r) >> 11) * (1.0 / 9007199254740992.0);
  double b = (double)(cr_next64(r) >> 11) * (1.0 / 9007199254740992.0);
  double c = (double)(cr_next64(r) >> 11) * (1.0 / 9007199254740992.0);
  bool ok = (a > 0.77395603) && (a < 0.77395607);
  ok = ok && (b > 0.43887842) && (b < 0.43887846);
  ok = ok && (c > 0.85859790) && (c < 0.85859794);
  return ok;
}
static_assert(canary_pcg42(), "CANARY_PCG_SEED42_RANDOM_MISMATCH");

// ---- compile-time circuit (WIRE indices; kind 0 RX,1 RY,2 RZ,3 CNOT) ------
struct COp { int kind; int a; int b; int slot; };
struct Circ { COp op[NOPS]; };

constexpr Circ build_circuit() {
  Circ c{};
  CRng r = cr_seed(42u);
  for (int i = 0; i < NOPS; i++) {
    int k = (int)cr_lemire32(r, 3u);            // integers(0,4)
    if (k == 3) {
      uint32_t v8 = cr_lemire32(r, 8u);         // Floyd j=8
      uint32_t v9 = cr_lemire32(r, 9u);         // Floyd j=9
      uint32_t i0 = v8;
      uint32_t i1 = (v9 == v8) ? 9u : v9;
      uint32_t j = cr_lemire32(r, 1u);          // shuffle swap bit
      if (j == 0u) { uint32_t t = i0; i0 = i1; i1 = t; }
      c.op[i] = COp{3, (int)i0, (int)i1, i};    // a=control, b=target
    } else {
      int w = (int)cr_lemire32(r, 9u);          // integers(0,10)
      c.op[i] = COp{k, w, 0, i};
    }
  }
  return c;
}
constexpr Circ CC = build_circuit();

// ---------------------------------------------------------------------------
// Compile-time Heisenberg propagation of H backward through the 30 ops.
// meta: xm[0:10) | zm[10:20) | sign[20] | w[21:25) | src[25:27)
// upk[u]: five 6-bit fields = byte offsets into runtime 16-entry per-wire-pair
// factor LUTs (eval).  pab/pu[j]: per-PATH packed data in a compile-time
// stride-P permuted order (coalesced reads + scattered u for LDS atomics):
//   pab[2j]   = g0|g1<<8|g2<<16|g3<<24  (6 groups of 5 op-slots, base-3 <243)
//   pab[2j+1] = g4|g5<<8 | w<<16 | src<<20 | sign<<22
//   pu[j]     = unique-string index for the atomicAdd target
// ---------------------------------------------------------------------------
constexpr int MAXP = 16384;
constexpr int MAXU = 4096;

struct Tables {
  int np, nu, overflow;
  uint32_t pmeta[MAXP]; uint32_t pcm[MAXP]; uint32_t psm[MAXP];
  uint32_t ukey[MAXU];  int ustart[MAXU + 1];
  uint32_t upk[MAXU];
  uint32_t pab[2 * MAXP]; uint16_t pu[MAXP];
};

constexpr Tables build_tables() {
  Tables T{};
  uint32_t meta[MAXP] = {}; uint32_t cm[MAXP] = {}; uint32_t sm[MAXP] = {};
  int np = 0; int ovf = 0;
  for (int w = 0; w < NW; w++)
    for (int src = 0; src < 3; src++) {         // 0:cZ->Z, 1:cX->X, 2:cY->Y
      uint32_t xm = (src != 0) ? (1u << w) : 0u;
      uint32_t zm = (src != 1) ? (1u << w) : 0u;
      meta[np] = xm | (zm << 10) | ((uint32_t)w << 21) | ((uint32_t)src << 25);
      cm[np] = 0u; sm[np] = 0u; np++;
    }
  for (int k = NOPS - 1; k >= 0 && !ovf; k--) {
    const COp op = CC.op[k];
    if (op.kind == 3) {
      const int c = op.a, t = op.b;
      for (int p = 0; p < np; p++) {
        uint32_t m = meta[p];
        uint32_t xm = m & 1023u, zm = (m >> 10) & 1023u;
        uint32_t xc = (xm >> c) & 1u, zc = (zm >> c) & 1u;
        uint32_t xt = (xm >> t) & 1u, zt = (zm >> t) & 1u;
        uint32_t fl = xc & zt & (1u ^ (xt ^ zc));
        xm ^= xc << t;
        zm ^= zt << c;
        m = (m & ~(1023u | (1023u << 10))) | xm | (zm << 10);
        m ^= fl << 20;
        meta[p] = m;
      }
    } else {
      const int q = op.a, ax = op.kind, bit = op.slot;
      const int n0 = np;
      for (int p = 0; p < n0; p++) {
        uint32_t m = meta[p];
        uint32_t x = (m >> q) & 1u;
        uint32_t z = (m >> (10 + q)) & 1u;
        uint32_t viol = (ax == 0) ? z : (ax == 1) ? (x ^ z) : x;
        if (viol) {
          uint32_t nx = 0, nz = 0, fl = 0;
          if (ax == 0)      { if (x) { nx = 0; nz = 1; fl = 1; } else { nx = 1; nz = 1; fl = 0; } }
          else if (ax == 1) { if (x) { nx = 0; nz = 1; fl = 0; } else { nx = 1; nz = 0; fl = 1; } }
          else              { if (z) { nx = 1; nz = 0; fl = 0; } else { nx = 1; nz = 1; fl = 1; } }
          if (np >= MAXP) { ovf = 1; break; }
          uint32_t m2 = m;
          m2 &= ~((1u << q) | (1u << (10 + q)));
          m2 |= (nx << q) | (nz << (10 + q));
          m2 ^= fl << 20;
          meta[np] = m2; cm[np] = cm[p]; sm[np] = sm[p] | (1u << bit);
          np++;
          cm[p] |= 1u << bit;
        }
      }
    }
  }
  if (ovf) { T.overflow = 1; return T; }
  // Y-kill compact
  int n2 = 0;
  for (int p = 0; p < np; p++) {
    uint32_t m = meta[p];
    if ((m & 1023u) & ((m >> 10) & 1023u)) continue;
    meta[n2] = m; cm[n2] = cm[p]; sm[n2] = sm[p]; n2++;
  }
  np = n2;
  // stable 2-pass radix sort of indices by 20-bit key
  int idx[MAXP] = {}; int tmp[MAXP] = {};
  for (int i = 0; i < np; i++) idx[i] = i;
  int hist[1025] = {};
  for (int i = 0; i < 1025; i++) hist[i] = 0;
  for (int i = 0; i < np; i++) hist[1 + (meta[idx[i]] & 1023u)]++;
  for (int i = 0; i < 1024; i++) hist[i + 1] += hist[i];
  for (int i = 0; i < np; i++) tmp[hist[meta[idx[i]] & 1023u]++] = idx[i];
  for (int i = 0; i < 1025; i++) hist[i] = 0;
  for (int i = 0; i < np; i++) hist[1 + ((meta[tmp[i]] >> 10) & 1023u)]++;
  for (int i = 0; i < 1024; i++) hist[i + 1] += hist[i];
  for (int i = 0; i < np; i++) idx[hist[(meta[tmp[i]] >> 10) & 1023u]++] = tmp[i];
  // group + emit (also records per-path unique index)
  uint16_t puTmp[MAXP] = {};
  int nu = 0; uint32_t prev = 0xFFFFFFFFu;
  for (int i = 0; i < np; i++) {
    int p = idx[i];
    uint32_t key = meta[p] & 0xFFFFFu;
    if (key != prev) {
      if (nu >= MAXU) { T.overflow = 2; return T; }
      T.ukey[nu] = key; T.ustart[nu] = i; prev = key; nu++;
    }
    T.pmeta[i] = meta[p]; T.pcm[i] = cm[p]; T.psm[i] = sm[p];
    puTmp[i] = (uint16_t)(nu - 1);
  }
  T.ustart[nu] = np;
  // pack per-unique-string pair-LUT byte offsets (5 pairs x 6 bits)
  for (int u = 0; u < nu; u++) {
    uint32_t key = T.ukey[u]; uint32_t pk = 0;
    for (int p = 0; p < 5; p++) {
      uint32_t x2 = (key >> (2 * p)) & 3u;
      uint32_t z2 = (key >> (10 + 2 * p)) & 3u;
      pk |= ((x2 | (z2 << 2)) << 2) << (6 * p);   // 4*code at bit 6p
    }
    T.upk[u] = pk;
  }
  // per-path packed group codes, stored stride-P permuted (coalesced reads,
  // scattered u -> collision-light LDS atomics).  P coprime with np.
  int P = 997;
  {
    bool ok = false;
    while (!ok) {
      int a = P, b = np;
      while (b) { int t2 = a % b; a = b; b = t2; }
      if (a == 1) ok = true; else P++;
    }
  }
  constexpr int POW3[5] = {1, 3, 9, 27, 81};
  for (int j = 0; j < np; j++) {
    int i = (int)(((long long)j * P) % np);      // source (sorted) index
    uint32_t cmv = T.pcm[i], smv = T.psm[i], m = T.pmeta[i];
    uint32_t g[6] = {0, 0, 0, 0, 0, 0};
    uint32_t mm = cmv;
    while (mm) { int b = __builtin_ctz(mm); mm &= mm - 1u; g[b / 5] += (uint32_t)POW3[b % 5]; }
    mm = smv;
    while (mm) { int b = __builtin_ctz(mm); mm &= mm - 1u; g[b / 5] += 2u * (uint32_t)POW3[b % 5]; }
    T.pab[2 * j]     = g[0] | (g[1] << 8) | (g[2] << 16) | (g[3] << 24);
    T.pab[2 * j + 1] = g[4] | (g[5] << 8) | (((m >> 21) & 15u) << 16)
                     | (((m >> 25) & 3u) << 20) | (((m >> 20) & 1u) << 22);
    T.pu[j] = puTmp[i];
  }
  T.np = np; T.nu = nu; T.overflow = 0;
  return T;
}

constexpr Tables TT = build_tables();
static_assert(TT.overflow == 0, "PAULI_PATH_OVERFLOW_raise_MAXP_or_pivot_to_runtime_tables");
static_assert(TT.nu >= 1 && TT.nu <= MAXU, "PAULI_UNIQUE_COUNT_OUT_OF_RANGE");
constexpr int NU  = TT.nu;
constexpr int NUP = (NU + 1) & ~1;   // pad to even so eval can do 2 strings/iter
constexpr int NP  = TT.np;

} // namespace

__device__ const Tables dTT = TT;

// ---------------------------------------------------------------------------
// FUSED kernel v3 (R4): 256 blocks x 1024 threads, 32 elements/block
// (TWO per wave).  R3 post-mortem: with >64 VGPR only 1 block/CU is resident,
// so R3's 512-block grid ran 2 sequential rounds per CU, paying the redundant
// prep (phases A-C) twice.  v3 halves the grid and gives each wave 2 elements:
// per-CU cost drops from 2x(prep + eval16) to 1x(prep + eval32); the eval
// loop's CKsh float4 load is also amortized across both elements.
// Phases: A trig/keys/Tbl x2/r2 | B G-LUT/r1 | C paths(atomic)+MLP | D eval x2
// ---------------------------------------------------------------------------
#define BLOCK 1024
#define WPB   32    // elements per block (2 per wave)
#define PWRK  (BLOCK - 16)

__global__ __launch_bounds__(BLOCK) void fused_kernel(
    const float* __restrict__ x,
    const float* __restrict__ rand_params,
    const float* __restrict__ rx_theta, const float* __restrict__ ry_theta,
    const float* __restrict__ head_w, const float* __restrict__ head_b,
    const float* __restrict__ w0, const float* __restrict__ b0,
    const float* __restrict__ w1, const float* __restrict__ b1,
    const float* __restrict__ w2, const float* __restrict__ b2,
    const float* __restrict__ w3, const float* __restrict__ b3,
    float* __restrict__ out, int bsz)
{
  __shared__ __align__(16) float2 CKsh[NUP];
  __shared__ float Gt[6 * 243];       // slot-group product LUT (prep)
  __shared__ float Tbl[WPB][80];      // per-element: 5 wire-pairs x 16 entries
  __shared__ float ct[32], st[32], abr[3], hwsh[10];
  __shared__ float r2[32], r1[64];
  __shared__ float MLPsh[NW + 1];

  const int tid  = threadIdx.x;
  const int wave = tid >> 6;
  const int lane = tid & 63;

  const int wvA = blockIdx.x * WPB + 2 * wave;      // this wave's two elements
  const int wvB = wvA + 1;
  const bool liveA = (wvA < bsz);
  const bool liveB = (wvB < bsz);
  const float* xeA = x + wvA * NW;
  const float* xeB = x + wvB * NW;
  float* tblA = Tbl[2 * wave];
  float* tblB = Tbl[2 * wave + 1];

  // ---- phase A: angle trig, tail fold, head_w, CK zero+keys, r2, Tbl x2 ----
  if (tid < NOPS) {
    float t = rand_params[tid];       // FULL angle for Heisenberg conjugation
    ct[tid] = cosf(t);
    st[tid] = sinf(t);
  } else if (tid == 32) {
    // O = M^dag Z M for M = RY(ty) @ RX(tx), Pauli coefficients.
    float tx = rx_theta[0], ty = ry_theta[0];
    abr[0] = cosf(tx) * cosf(ty);     // cZ
    abr[1] = -sinf(ty);               // cX
    abr[2] = sinf(tx) * cosf(ty);     // cY
  } else if (tid >= 40 && tid < 40 + NW) {
    hwsh[tid - 40] = head_w[tid - 40];
  } else if (tid >= 64 && tid < 96) {
    const int j = tid - 64;
    float acc = 0.f;
    for (int k = 0; k < 16; k++) acc += w3[k] * w2[k * 32 + j];
    r2[j] = acc;
  }
  for (int i = tid; i < NUP; i += BLOCK)
    CKsh[i] = make_float2(0.f, __uint_as_float(i < NU ? dTT.upk[i] : 0u));
  // per-element wire-pair LUTs: entry e = p*16 + code; code = x2 | z2<<2
  if (liveA) {
    {
      const int e = lane;
      const int p = e >> 4, code = e & 15;
      float2 xv = *(const float2*)(xeA + 2 * p);          // 8B-aligned (40B rows)
      float c0 = __cosf(xv.x), s0 = __sinf(xv.x);
      float c1 = __cosf(xv.y), s1 = __sinf(xv.y);
      float f0 = (code & 1) ? s0 : ((code & 4) ? c0 : 1.0f);
      float f1 = (code & 2) ? s1 : ((code & 8) ? c1 : 1.0f);
      tblA[e] = f0 * f1;
    }
    if (lane < 16) {
      const int e = lane + 64;
      const int p = e >> 4, code = e & 15;
      float2 xv = *(const float2*)(xeA + 2 * p);
      float c0 = __cosf(xv.x), s0 = __sinf(xv.x);
      float c1 = __cosf(xv.y), s1 = __sinf(xv.y);
      float f0 = (code & 1) ? s0 : ((code & 4) ? c0 : 1.0f);
      float f1 = (code & 2) ? s1 : ((code & 8) ? c1 : 1.0f);
      tblA[e] = f0 * f1;
    }
  }
  if (liveB) {
    {
      const int e = lane;
      const int p = e >> 4, code = e & 15;
      float2 xv = *(const float2*)(xeB + 2 * p);
      float c0 = __cosf(xv.x), s0 = __sinf(xv.x);
      float c1 = __cosf(xv.y), s1 = __sinf(xv.y);
      float f0 = (code & 1) ? s0 : ((code & 4) ? c0 : 1.0f);
      float f1 = (code & 2) ? s1 : ((code & 8) ? c1 : 1.0f);
      tblB[e] = f0 * f1;
    }
    if (lane < 16) {
      const int e = lane + 64;
      const int p = e >> 4, code = e & 15;
      float2 xv = *(const float2*)(xeB + 2 * p);
      float c0 = __cosf(xv.x), s0 = __sinf(xv.x);
      float c1 = __cosf(xv.y), s1 = __sinf(xv.y);
      float f0 = (code & 1) ? s0 : ((code & 4) ? c0 : 1.0f);
      float f1 = (code & 2) ? s1 : ((code & 8) ? c1 : 1.0f);
      tblB[e] = f0 * f1;
    }
  }
  __syncthreads();

  // ---- phase B: slot-group product LUT; r1 ----
  for (int e = tid; e < 6 * 243; e += BLOCK) {
    const int g = e / 243;
    int c = e - g * 243;
    float v = 1.f;
#pragma unroll
    for (int j = 0; j < 5; j++) {
      int tr = c % 3; c /= 3;
      if (tr == 1) v *= ct[5 * g + j];
      else if (tr == 2) v *= st[5 * g + j];
    }
    Gt[e] = v;
  }
  if (tid >= BLOCK - 64) {
    const int j = tid - (BLOCK - 64);
    float acc = 0.f;
    for (int k = 0; k < 32; k++) acc += r2[k] * w1[k * 64 + j];
    r1[j] = acc;
  }
  __syncthreads();

  // ---- phase C: balanced path scatter (atomic) ; MLP finals ----
  if (tid < NW) {
    float acc = 0.f;
    for (int k = 0; k < 64; k++) acc += r1[k] * w0[k * NW + tid];
    MLPsh[tid] = acc;
  } else if (tid == NW) {
    float acc = b3[0] + head_b[0];
    for (int k = 0; k < 16; k++) acc += w3[k] * b2[k];
    for (int k = 0; k < 32; k++) acc += r2[k] * b1[k];
    for (int k = 0; k < 64; k++) acc += r1[k] * b0[k];
    MLPsh[NW] = acc;
  } else if (tid >= 16) {
#pragma unroll 2
    for (int i = tid - 16; i < NP; i += PWRK) {
      uint2 pp = *(const uint2*)&dTT.pab[2 * i];
      uint32_t pa = pp.x, pb = pp.y;
      int      u  = (int)dTT.pu[i];
      float v = hwsh[(pb >> 16) & 15u] * abr[(pb >> 20) & 3u];
      if (pb & (1u << 22)) v = -v;
      v *= Gt[         (pa       ) & 255u] * Gt[1 * 243 + ((pa >>  8) & 255u)];
      v *= Gt[2 * 243 + ((pa >> 16) & 255u)] * Gt[3 * 243 + ( pa >> 24        )];
      v *= Gt[4 * 243 + ( pb        & 255u)] * Gt[5 * 243 + ((pb >>  8) & 255u)];
      atomicAdd(&CKsh[u].x, v);
    }
  }
  __syncthreads();
  if (!liveA) return;

  // ---- phase D: eval (2 strings x 2 elements per iter; CK load amortized) --
  const char* tA = (const char*)tblA;
  const char* tB = (const char*)tblB;
  float aA0 = 0.f, aA1 = 0.f, aB0 = 0.f, aB1 = 0.f;
#pragma unroll 4
  for (int s = 2 * lane; s < NUP; s += 128) {
    float4 q = *(const float4*)&CKsh[s];          // strings s, s+1
    uint32_t ka = __float_as_uint(q.y);
    uint32_t kb = __float_as_uint(q.w);
    uint32_t o0 =  ka        & 63u, o1 = (ka >>  6) & 63u, o2 = (ka >> 12) & 63u,
             o3 = (ka >> 18) & 63u, o4 = (ka >> 24) & 63u;
    uint32_t p0 =  kb        & 63u, p1 = (kb >>  6) & 63u, p2 = (kb >> 12) & 63u,
             p3 = (kb >> 18) & 63u, p4 = (kb >> 24) & 63u;
    float fA0 = *(const float*)(tA + o0) * *(const float*)(tA + 64 + o1)
              * *(const float*)(tA + 128 + o2) * *(const float*)(tA + 192 + o3)
              * *(const float*)(tA + 256 + o4);
    float fA1 = *(const float*)(tA + p0) * *(const float*)(tA + 64 + p1)
              * *(const float*)(tA + 128 + p2) * *(const float*)(tA + 192 + p3)
              * *(const float*)(tA + 256 + p4);
    float fB0 = *(const float*)(tB + o0) * *(const float*)(tB + 64 + o1)
              * *(const float*)(tB + 128 + o2) * *(const float*)(tB + 192 + o3)
              * *(const float*)(tB + 256 + o4);
    float fB1 = *(const float*)(tB + p0) * *(const float*)(tB + 64 + p1)
              * *(const float*)(tB + 128 + p2) * *(const float*)(tB + 192 + p3)
              * *(const float*)(tB + 256 + p4);
    aA0 = fmaf(q.x, fA0, aA0);
    aA1 = fmaf(q.z, fA1, aA1);
    aB0 = fmaf(q.x, fB0, aB0);
    aB1 = fmaf(q.z, fB1, aB1);
  }
  float accA = aA0 + aA1;
  float accB = aB0 + aB1;

#pragma unroll
  for (int m = 1; m < 64; m <<= 1) {
    accA += __shfl_xor(accA, m);
    accB += __shfl_xor(accB, m);
  }

  if (lane == 0) {
    float ccA = MLPsh[NW];
#pragma unroll
    for (int w = 0; w < NW; w++) ccA += xeA[w] * MLPsh[w];
    out[wvA] = accA + ccA;
    if (liveB) {
      float ccB = MLPsh[NW];
#pragma unroll
      for (int w = 0; w < NW; w++) ccB += xeB[w] * MLPsh[w];
      out[wvB] = accB + ccB;
    }
  }
}

extern "C" void kernel_launch(void* const* d_in, const int* in_sizes, int n_in,
                              void* d_out, int out_size, void* d_ws, size_t ws_size,
                              hipStream_t stream) {
  const float* x   = (const float*)d_in[0];
  const float* rp  = (const float*)d_in[1];
  const float* rxT = (const float*)d_in[2];
  const float* ryT = (const float*)d_in[3];
  const float* hw  = (const float*)d_in[4];
  const float* hb  = (const float*)d_in[5];
  const float* w0  = (const float*)d_in[6];
  const float* b0  = (const float*)d_in[7];
  const float* w1  = (const float*)d_in[8];
  const float* b1  = (const float*)d_in[9];
  const float* w2  = (const float*)d_in[10];
  const float* b2  = (const float*)d_in[11];
  const float* w3  = (const float*)d_in[12];
  const float* b3  = (const float*)d_in[13];
  const int bsz = in_sizes[0] / NW;

  const int blocks = (bsz + WPB - 1) / WPB;   // 256 blocks @ bsz=8192 -> 1/CU
  hipLaunchKernelGGL(fused_kernel, dim3(blocks), dim3(BLOCK), 0, stream,
                     x, rp, rxT, ryT, hw, hb, w0, b0, w1, b1, w2, b2, w3, b3,
                     (float*)d_out, bsz);
}